// Round 1
// baseline (504.320 us; speedup 1.0000x reference)
//
#include <hip/hip_runtime.h>
#include <hip/hip_bf16.h>
#include <stdint.h>

// Problem dims
#define Bn  8
#define Ln  4096
#define DHn 1024
#define Tn  1024
#define DGn 768
#define Pn  256

typedef float  f32x4  __attribute__((ext_vector_type(4)));
typedef __bf16 bf16x8 __attribute__((ext_vector_type(8)));

__device__ __forceinline__ void gload16(const void* g, void* l) {
  __builtin_amdgcn_global_load_lds(
      (const __attribute__((address_space(1))) void*)g,
      (__attribute__((address_space(3))) void*)l, 16, 0, 0);
}

__device__ __forceinline__ unsigned short f2bf(float x) {
  union { float f; uint32_t u; } v; v.f = x;
  uint32_t u = v.u;
  return (unsigned short)((u + 0x7FFFu + ((u >> 16) & 1u)) >> 16);
}

__device__ __forceinline__ float bf2f(unsigned short b) {
  union { uint32_t u; float f; } v; v.u = ((uint32_t)b) << 16;
  return v.f;
}

// ---------------- fp32 -> bf16 convert (vectorized) ----------------
__global__ void cvt_kernel(const float4* __restrict__ in,
                           ushort4* __restrict__ out, int n4) {
  int i = blockIdx.x * 256 + threadIdx.x;
  if (i < n4) {
    float4 v = in[i];
    ushort4 o;
    o.x = f2bf(v.x); o.y = f2bf(v.y); o.z = f2bf(v.z); o.w = f2bf(v.w);
    out[i] = o;
  }
}

// ------------- H [B,L,DH] fp32 -> HT [B,DH,L] bf16 (tiled transpose) -------------
__global__ void transpose_cvt(const float* __restrict__ Hg,
                              unsigned short* __restrict__ HT) {
  __shared__ unsigned short tile[64 * 65];
  const int b  = blockIdx.z;
  const int l0 = blockIdx.x * 64;
  const int d0 = blockIdx.y * 64;
  const float4* src = (const float4*)(Hg + (size_t)b * Ln * DHn);
  for (int e = threadIdx.x; e < 1024; e += 256) {
    int l  = e >> 4;
    int d4 = e & 15;
    float4 v = src[((size_t)(l0 + l) * DHn + d0) / 4 + d4];
    int d = d4 * 4;
    tile[(d + 0) * 65 + l] = f2bf(v.x);
    tile[(d + 1) * 65 + l] = f2bf(v.y);
    tile[(d + 2) * 65 + l] = f2bf(v.z);
    tile[(d + 3) * 65 + l] = f2bf(v.w);
  }
  __syncthreads();
  ushort4* dst = (ushort4*)(HT + (size_t)b * DHn * Ln);
  for (int e = threadIdx.x; e < 1024; e += 256) {
    int d  = e >> 4;
    int l4 = (e & 15) * 4;
    ushort4 o;
    o.x = tile[d * 65 + l4 + 0];
    o.y = tile[d * 65 + l4 + 1];
    o.z = tile[d * 65 + l4 + 2];
    o.w = tile[d * 65 + l4 + 3];
    dst[((size_t)(d0 + d) * Ln + l0) / 4 + (e & 15)] = o;
  }
}

// ---------------- bt-GEMM: C[m,n] = sum_k A[m,k]*B[n,k], 128x128 tile ----------------
// EPI 0: C bf16 = acc
// EPI 1: C bf16 = exp(acc*scale), row-sums atomically added into S
// EPI 2: C fp32 = acc / (S[row] + 1e-8)
template <int EPI>
__global__ __launch_bounds__(256) void gemm_bt(
    const unsigned short* __restrict__ A, const unsigned short* __restrict__ B,
    void* __restrict__ Cout, float* __restrict__ S,
    int K, int lda, int ldb, int ldc,
    long sA, long sB, long sC, int sS, float scale) {
  __shared__ unsigned short As[128 * 32];
  __shared__ unsigned short Bs[128 * 32];
  const int b = blockIdx.z;
  const unsigned short* Ab = A + (long)b * sA;
  const unsigned short* Bb = B + (long)b * sB;
  const int m0 = blockIdx.x * 128;
  const int n0 = blockIdx.y * 128;
  const int tid  = threadIdx.x;
  const int lane = tid & 63;
  const int wave = tid >> 6;
  const int wm = (wave >> 1) << 6;   // wave's 64x64 subtile
  const int wn = (wave & 1) << 6;
  const int lrow = lane & 15;
  const int quad = lane >> 4;
  const int srow0 = lane >> 2;       // staging: row within 16-row chunk
  const int skcol = (lane & 3) << 3; // staging: k offset (x8 bf16 = 16B)

  f32x4 acc[4][4];
#pragma unroll
  for (int mt = 0; mt < 4; ++mt)
#pragma unroll
    for (int nt = 0; nt < 4; ++nt) acc[mt][nt] = f32x4{0.f, 0.f, 0.f, 0.f};

  for (int k0 = 0; k0 < K; k0 += 32) {
    __syncthreads();
#pragma unroll
    for (int j = 0; j < 2; ++j) {
      int c = wave * 2 + j;          // 8 chunks of 16 rows
      int row = c * 16 + srow0;
      gload16(Ab + (size_t)(m0 + row) * lda + (k0 + skcol), &As[c * 512]);
      gload16(Bb + (size_t)(n0 + row) * ldb + (k0 + skcol), &Bs[c * 512]);
    }
    __syncthreads();
    bf16x8 af[4], bfr[4];
#pragma unroll
    for (int mt = 0; mt < 4; ++mt)
      af[mt] = *(const bf16x8*)&As[(wm + mt * 16 + lrow) * 32 + quad * 8];
#pragma unroll
    for (int nt = 0; nt < 4; ++nt)
      bfr[nt] = *(const bf16x8*)&Bs[(wn + nt * 16 + lrow) * 32 + quad * 8];
#pragma unroll
    for (int mt = 0; mt < 4; ++mt)
#pragma unroll
      for (int nt = 0; nt < 4; ++nt)
        acc[mt][nt] = __builtin_amdgcn_mfma_f32_16x16x32_bf16(
            af[mt], bfr[nt], acc[mt][nt], 0, 0, 0);
  }

  // C/D layout (verified m89/m91): col = lane&15, row = quad*4 + reg
  if (EPI == 0) {
    unsigned short* C = (unsigned short*)Cout + (long)b * sC;
#pragma unroll
    for (int mt = 0; mt < 4; ++mt)
#pragma unroll
      for (int r = 0; r < 4; ++r) {
        int row = m0 + wm + mt * 16 + quad * 4 + r;
        unsigned short* Cr = C + (size_t)row * ldc + n0 + wn + lrow;
#pragma unroll
        for (int nt = 0; nt < 4; ++nt) Cr[nt * 16] = f2bf(acc[mt][nt][r]);
      }
  } else if (EPI == 1) {
    unsigned short* C = (unsigned short*)Cout + (long)b * sC;
    float* Sb = S + (long)b * sS;
#pragma unroll
    for (int mt = 0; mt < 4; ++mt)
#pragma unroll
      for (int r = 0; r < 4; ++r) {
        int row = m0 + wm + mt * 16 + quad * 4 + r;
        unsigned short* Cr = C + (size_t)row * ldc + n0 + wn + lrow;
        float psum = 0.f;
#pragma unroll
        for (int nt = 0; nt < 4; ++nt) {
          float e = __expf(acc[mt][nt][r] * scale);
          unsigned short bv = f2bf(e);
          Cr[nt * 16] = bv;
          psum += bf2f(bv);  // sum the value we actually stored
        }
        psum += __shfl_xor(psum, 1);
        psum += __shfl_xor(psum, 2);
        psum += __shfl_xor(psum, 4);
        psum += __shfl_xor(psum, 8);
        if (lrow == 0) atomicAdd(&Sb[row], psum);
      }
  } else {
    float* C = (float*)Cout + (long)b * sC;
    const float* Sb = S + (long)b * sS;
#pragma unroll
    for (int mt = 0; mt < 4; ++mt)
#pragma unroll
      for (int r = 0; r < 4; ++r) {
        int row = m0 + wm + mt * 16 + quad * 4 + r;
        float inv = 1.f / (Sb[row] + 1e-8f);
        float* Cr = C + (size_t)row * ldc + n0 + wn + lrow;
#pragma unroll
        for (int nt = 0; nt < 4; ++nt) Cr[nt * 16] = acc[mt][nt][r] * inv;
      }
  }
}

extern "C" void kernel_launch(void* const* d_in, const int* in_sizes, int n_in,
                              void* d_out, int out_size, void* d_ws, size_t ws_size,
                              hipStream_t stream) {
  const float* H  = (const float*)d_in[0];
  const float* G  = (const float*)d_in[1];
  const float* Wq = (const float*)d_in[2];
  const float* Wk = (const float*)d_in[3];
  float* out = (float*)d_out;

  char* ws = (char*)d_ws;
  size_t off = 0;
  auto alloc = [&](size_t bytes) {
    void* p = ws + off;
    off = (off + bytes + 255) & ~(size_t)255;
    return p;
  };
  unsigned short* Hb  = (unsigned short*)alloc((size_t)Bn * Ln * DHn * 2); // 64MB
  unsigned short* HbT = (unsigned short*)alloc((size_t)Bn * DHn * Ln * 2); // 64MB
  unsigned short* Gb  = (unsigned short*)alloc((size_t)Bn * Tn * DGn * 2); // 12MB
  unsigned short* Wqb = (unsigned short*)alloc((size_t)Pn * DGn * 2);
  unsigned short* Wkb = (unsigned short*)alloc((size_t)Pn * DHn * 2);
  unsigned short* Kb  = (unsigned short*)alloc((size_t)Bn * Ln * Pn * 2);  // 16MB
  unsigned short* Qb  = (unsigned short*)alloc((size_t)Bn * Tn * Pn * 2);  // 4MB
  float* Sv           = (float*)alloc((size_t)Bn * Tn * 4);                // 32KB
  // P [B,T,L] bf16 (64MB) aliases Hb: Hb is dead after K-proj, and same-stream
  // kernels serialize, so QK's writes can't race K-proj's reads.
  unsigned short* Pm = Hb;

  // 1) converts
  {
    int n4 = Bn * Ln * DHn / 4;
    cvt_kernel<<<(n4 + 255) / 256, 256, 0, stream>>>((const float4*)H, (ushort4*)Hb, n4);
  }
  {
    int n4 = Bn * Tn * DGn / 4;
    cvt_kernel<<<(n4 + 255) / 256, 256, 0, stream>>>((const float4*)G, (ushort4*)Gb, n4);
  }
  {
    int n4 = Pn * DGn / 4;
    cvt_kernel<<<(n4 + 255) / 256, 256, 0, stream>>>((const float4*)Wq, (ushort4*)Wqb, n4);
  }
  {
    int n4 = Pn * DHn / 4;
    cvt_kernel<<<(n4 + 255) / 256, 256, 0, stream>>>((const float4*)Wk, (ushort4*)Wkb, n4);
  }
  // 2) H transpose-convert
  transpose_cvt<<<dim3(Ln / 64, DHn / 64, Bn), 256, 0, stream>>>(H, HbT);
  // 3) zero softmax sums
  hipMemsetAsync(Sv, 0, (size_t)Bn * Tn * 4, stream);

  // 4) K = H Wk^T : [L,P] per batch
  gemm_bt<0><<<dim3(Ln / 128, Pn / 128, Bn), 256, 0, stream>>>(
      Hb, Wkb, Kb, nullptr, DHn, DHn, DHn, Pn,
      (long)Ln * DHn, 0L, (long)Ln * Pn, 0, 1.f);
  // 5) Q = G Wq^T : [T,P] per batch
  gemm_bt<0><<<dim3(Tn / 128, Pn / 128, Bn), 256, 0, stream>>>(
      Gb, Wqb, Qb, nullptr, DGn, DGn, DGn, Pn,
      (long)Tn * DGn, 0L, (long)Tn * Pn, 0, 1.f);
  // 6) P = exp(scale * Q K^T) : [T,L] per batch, + row sums into Sv
  gemm_bt<1><<<dim3(Tn / 128, Ln / 128, Bn), 256, 0, stream>>>(
      Qb, Kb, Pm, Sv, Pn, Pn, Pn, Ln,
      (long)Tn * Pn, (long)Ln * Pn, (long)Tn * Ln, Tn, 0.0625f);
  // 7) Z = (P H) / (s + eps) : [T,DH] per batch, fp32 out
  gemm_bt<2><<<dim3(Tn / 128, DHn / 128, Bn), 256, 0, stream>>>(
      Pm, HbT, out, Sv, Ln, Ln, Ln, DHn,
      (long)Tn * Ln, (long)DHn * Ln, (long)Tn * DHn, Tn, 1.f);
}